// Round 10
// baseline (418.199 us; speedup 1.0000x reference)
//
#include <hip/hip_runtime.h>
#include <float.h>
#include <math.h>

#define NN 8192
#define DH 256
#define KNN 10
#define TSTEPS 10
#define EPSC 0.1f
#define CTILE 1024          // candidates staged in LDS per tile
#define QPB 16              // queries per block (16 waves of 64)

typedef short s8v __attribute__((ext_vector_type(8)));
typedef float f4v __attribute__((ext_vector_type(4)));

__device__ __forceinline__ float bf2f(unsigned short u) {
    union { unsigned u; float f; } c; c.u = ((unsigned)u) << 16; return c.f;
}
__device__ __forceinline__ unsigned short f2bf(float f) {
    union { float f; unsigned u; } c; c.f = f;
    unsigned r = c.u + 0x7FFF + ((c.u >> 16) & 1);
    return (unsigned short)(r >> 16);
}

// -------- conv_ws [3][256][256] (k,n) -> FRAGMENT-MAJOR bf16 Wt ---------------
// frag = (kc*2+ks)*16 + nb. Lane layout matches the MFMA B operand exactly;
// a wave's B load = 1KB contiguous (fully coalesced), no LDS staging needed.
__global__ void prep_wt(const float* __restrict__ W, unsigned short* __restrict__ Wt) {
    int e = blockIdx.x * 256 + threadIdx.x;     // 768*256 = 196608
    int i8 = e & 7, lane = (e >> 3) & 63, nb = (e >> 9) & 15;
    int ks = (e >> 13) & 1, kc2 = (e >> 14) & 3, g = e >> 16;
    int quad = lane >> 4, l15 = lane & 15;
    int k = kc2 * 64 + ks * 32 + quad * 8 + i8;
    int n = nb * 16 + l15;
    Wt[e] = f2bf(W[g * 65536 + k * 256 + n]);
}

// ---------------- pos4[j] = {x, y, z, |p|^2} ----------------------------------
__global__ void prep_pos(const float* __restrict__ pos, float4* __restrict__ pos4) {
    int j = blockIdx.x * 256 + threadIdx.x;
    float x = pos[j * 3], y = pos[j * 3 + 1], z = pos[j * 3 + 2];
    float4 v; v.x = x; v.y = y; v.z = z; v.w = x * x + y * y + z * z;
    pos4[j] = v;
}

// ---------------- kNN: 1 wave/query, 16 queries/block, DPP-insert pops --------
// Measured ~55us (R7-R9). Kept as-is.
__launch_bounds__(1024)
__global__ void knn_wave(const float* __restrict__ pos, const float4* __restrict__ pos4,
                         int* __restrict__ nbr) {
    __shared__ float4 cand[CTILE];
    int tid = threadIdx.x;
    int wv = tid >> 6, lane = tid & 63;
    int i = blockIdx.x * QPB + wv;               // query for this wave
    float xi = pos[i * 3], yi = pos[i * 3 + 1], zi = pos[i * 3 + 2];
    float sqi = xi * xi + yi * yi + zi * zi;
    int igrp = i & ~63;                          // the only 64-group containing i

    float b  = FLT_MAX;                          // rank 'lane' distance
    int   ib = -1;                               // rank 'lane' index
    float thr = FLT_MAX;                         // 10th best (b at lane 9)

    for (int tile = 0; tile < NN / CTILE; ++tile) {
        __syncthreads();
        cand[tid] = pos4[tile * CTILE + tid];    // 1024 threads, 1 float4 each
        __syncthreads();
#pragma unroll 4
        for (int u = 0; u < CTILE / 64; ++u) {
            int jgrp = tile * CTILE + u * 64;
            float4 c = cand[u * 64 + lane];
            int j = jgrp + lane;
            float m = c.x * xi + c.y * yi + c.z * zi;
            float d = (sqi + c.w) - 2.0f * m;
            if (jgrp == igrp) {                  // wave-uniform branch
                if (j == i) d = FLT_MAX;         // self-exclusion, one batch only
            }
            unsigned long long mask = __ballot(d < thr);
            while (mask) {
                int l = __ffsll((unsigned long long)mask) - 1;
                mask &= mask - 1;
                float dc = __int_as_float(__builtin_amdgcn_readlane(__float_as_int(d), l));
                if (dc < thr) {                  // recheck vs updated threshold
                    int jc = __builtin_amdgcn_readlane(j, l);
                    // shift-down neighbors via DPP row_shr:1 (lane r <- r-1)
                    float bp = __int_as_float(__builtin_amdgcn_update_dpp(
                        0, __float_as_int(b), 0x111, 0xF, 0xF, true));
                    int ip = __builtin_amdgcn_update_dpp(0, ib, 0x111, 0xF, 0xF, true);
                    bool c0 = dc < b;                    // insert at/below my rank
                    bool cp = (lane != 0) && (dc < bp);  // insert strictly below
                    b  = c0 ? (cp ? bp : dc) : b;
                    ib = c0 ? (cp ? ip : jc) : ib;
                    thr = __int_as_float(__builtin_amdgcn_readlane(__float_as_int(b), 9));
                }
            }
        }
    }
    if (lane < KNN) nbr[i * KNN + lane] = ib;    // rank r already in lane r
}

// ---------------- h = lm@emb_w + emb_b ; x = h@rw + rb ------------------------
__global__ void emb_kernel(const float* __restrict__ lm, const float* __restrict__ ew,
                           const float* __restrict__ eb, const float* __restrict__ rw,
                           const float* __restrict__ rb,
                           float* __restrict__ hdo, unsigned short* __restrict__ hbf,
                           float* __restrict__ xout) {
    __shared__ float s0[4], s1[4], s2[4];
    int i = blockIdx.x, d = threadIdx.x;
    float a0 = lm[i * 3], a1 = lm[i * 3 + 1], a2 = lm[i * 3 + 2];
    float h = eb[d] + a0 * ew[d] + a1 * ew[256 + d] + a2 * ew[512 + d];
    hdo[i * 256 + d] = h;
    hbf[i * 256 + d] = f2bf(h);
    float p0 = h * rw[d * 3], p1 = h * rw[d * 3 + 1], p2 = h * rw[d * 3 + 2];
    for (int off = 32; off; off >>= 1) {
        p0 += __shfl_down(p0, off, 64);
        p1 += __shfl_down(p1, off, 64);
        p2 += __shfl_down(p2, off, 64);
    }
    int lane = d & 63, wid = d >> 6;
    if (lane == 0) { s0[wid] = p0; s1[wid] = p1; s2[wid] = p2; }
    __syncthreads();
    if (d == 0) {
        xout[i * 3 + 0] = s0[0] + s0[1] + s0[2] + s0[3] + rb[0];
        xout[i * 3 + 1] = s1[0] + s1[1] + s1[2] + s1[3] + rb[1];
        xout[i * 3 + 2] = s2[0] + s2[1] + s2[2] + s2[3] + rb[2];
    }
}

// ---------------- hop-1: x1[i] = 0.1 * sum_{j in nbr(i)} hbf[j] ---------------
__global__ void agg_kernel(const unsigned short* __restrict__ src,
                           unsigned short* __restrict__ dst,
                           const int* __restrict__ nbr) {
    int tid = threadIdx.x;
    int slot = tid >> 5, l32 = tid & 31;
    int node = blockIdx.x * 8 + slot;
    int d0 = l32 * 8;
    const int* nb = nbr + node * KNN;
    int j[KNN];
#pragma unroll
    for (int q = 0; q < KNN; q++) j[q] = nb[q];
    uint4 v[KNN];
#pragma unroll
    for (int q = 0; q < KNN; q++) v[q] = *(const uint4*)(src + j[q] * 256 + d0);
    float a[8];
#pragma unroll
    for (int e = 0; e < 8; e++) a[e] = 0.f;
#pragma unroll
    for (int q = 0; q < KNN; q++) {
        a[0] += bf2f((unsigned short)(v[q].x & 0xffff));
        a[1] += bf2f((unsigned short)(v[q].x >> 16));
        a[2] += bf2f((unsigned short)(v[q].y & 0xffff));
        a[3] += bf2f((unsigned short)(v[q].y >> 16));
        a[4] += bf2f((unsigned short)(v[q].z & 0xffff));
        a[5] += bf2f((unsigned short)(v[q].z >> 16));
        a[6] += bf2f((unsigned short)(v[q].w & 0xffff));
        a[7] += bf2f((unsigned short)(v[q].w >> 16));
    }
    uint4 o;
    o.x = (unsigned)f2bf(a[0]*0.1f) | ((unsigned)f2bf(a[1]*0.1f) << 16);
    o.y = (unsigned)f2bf(a[2]*0.1f) | ((unsigned)f2bf(a[3]*0.1f) << 16);
    o.z = (unsigned)f2bf(a[4]*0.1f) | ((unsigned)f2bf(a[5]*0.1f) << 16);
    o.w = (unsigned)f2bf(a[6]*0.1f) | ((unsigned)f2bf(a[7]*0.1f) << 16);
    *(uint4*)(dst + node * 256 + d0) = o;
}

// ------- fused: hop-2 gather + BARRIER-FREE-K GEMM (32 rows/wave) -------------
// M32 x N256, 512 threads (8 waves), grid 256 (1 block/CU). Wave w owns
// 32 rows x 32 cols (acc[4]): each B fragment now feeds FOUR MFMAs (2 row-
// tiles x reuse), halving B L2 traffic 196->98MB/dispatch and doubling the
// MFMA:load ratio. K-loop still barrier-free (2 barriers total in kernel).
// K order per output: kc 0..11, ks 0..1 ascending => bit-identical.
__launch_bounds__(512, 2)
__global__ void gemm_step(unsigned short* hbf,
                          const unsigned short* __restrict__ x1,
                          const int* __restrict__ nbr,
                          const unsigned short* __restrict__ Wt,
                          const float* __restrict__ cb,
                          const float* __restrict__ rw, const float* __restrict__ rb,
                          float* hdo, float* __restrict__ yout, float* yfin) {
    __shared__ __align__(16) short Ah[32 * 264];
    __shared__ __align__(16) short A1[32 * 264];
    __shared__ __align__(16) short X2[32 * 264];
    __shared__ float rwl[768];
    __shared__ float cbl[256];
    __shared__ float yred[8][2][4][4][3];  // [wave][rt][quad][r][xyz]

    int tid = threadIdx.x;
    int m0 = blockIdx.x * 32;
    for (int idx = tid; idx < 768; idx += 512) rwl[idx] = rw[idx];
    if (tid < 256) cbl[tid] = cb[tid];

    int w = tid >> 6, lane = tid & 63;
    int quad = lane >> 4, l15 = lane & 15;
    int row = tid >> 4, cg = tid & 15;            // stage: 32 rows x 16 thr, 16 shorts each

    // ---- stage A for hop0 (hbf) and hop1 (x1): 2x uint4 per thread -----------
    {
        const unsigned short* hsrc = ((const unsigned short*)hbf) + (m0 + row) * 256 + cg * 16;
        uint4 va0 = *(const uint4*)(hsrc);
        uint4 va1 = *(const uint4*)(hsrc + 8);
        *(uint4*)((unsigned short*)&Ah[row * 264 + cg * 16]) = va0;
        *(uint4*)((unsigned short*)&Ah[row * 264 + cg * 16 + 8]) = va1;
        const unsigned short* xsrc = x1 + (m0 + row) * 256 + cg * 16;
        uint4 vb0 = *(const uint4*)(xsrc);
        uint4 vb1 = *(const uint4*)(xsrc + 8);
        *(uint4*)((unsigned short*)&A1[row * 264 + cg * 16]) = vb0;
        *(uint4*)((unsigned short*)&A1[row * 264 + cg * 16 + 8]) = vb1;
    }
    // ---- hop-2 gather: X2[row][:] = bf16(0.1 * sum x1[nbr[row]]) -------------
    {
        const int* nb = nbr + (m0 + row) * KNN;
        int j[KNN];
#pragma unroll
        for (int q = 0; q < KNN; q++) j[q] = nb[q];
        float a[16];
#pragma unroll
        for (int e = 0; e < 16; e++) a[e] = 0.f;
#pragma unroll
        for (int q = 0; q < KNN; q++) {
            const unsigned short* p = x1 + j[q] * 256 + cg * 16;
            uint4 v0 = *(const uint4*)(p);
            uint4 v1 = *(const uint4*)(p + 8);
            a[0]  += bf2f((unsigned short)(v0.x & 0xffff));
            a[1]  += bf2f((unsigned short)(v0.x >> 16));
            a[2]  += bf2f((unsigned short)(v0.y & 0xffff));
            a[3]  += bf2f((unsigned short)(v0.y >> 16));
            a[4]  += bf2f((unsigned short)(v0.z & 0xffff));
            a[5]  += bf2f((unsigned short)(v0.z >> 16));
            a[6]  += bf2f((unsigned short)(v0.w & 0xffff));
            a[7]  += bf2f((unsigned short)(v0.w >> 16));
            a[8]  += bf2f((unsigned short)(v1.x & 0xffff));
            a[9]  += bf2f((unsigned short)(v1.x >> 16));
            a[10] += bf2f((unsigned short)(v1.y & 0xffff));
            a[11] += bf2f((unsigned short)(v1.y >> 16));
            a[12] += bf2f((unsigned short)(v1.z & 0xffff));
            a[13] += bf2f((unsigned short)(v1.z >> 16));
            a[14] += bf2f((unsigned short)(v1.w & 0xffff));
            a[15] += bf2f((unsigned short)(v1.w >> 16));
        }
        uint4 o0, o1;
        o0.x = (unsigned)f2bf(a[0]*0.1f)  | ((unsigned)f2bf(a[1]*0.1f)  << 16);
        o0.y = (unsigned)f2bf(a[2]*0.1f)  | ((unsigned)f2bf(a[3]*0.1f)  << 16);
        o0.z = (unsigned)f2bf(a[4]*0.1f)  | ((unsigned)f2bf(a[5]*0.1f)  << 16);
        o0.w = (unsigned)f2bf(a[6]*0.1f)  | ((unsigned)f2bf(a[7]*0.1f)  << 16);
        o1.x = (unsigned)f2bf(a[8]*0.1f)  | ((unsigned)f2bf(a[9]*0.1f)  << 16);
        o1.y = (unsigned)f2bf(a[10]*0.1f) | ((unsigned)f2bf(a[11]*0.1f) << 16);
        o1.z = (unsigned)f2bf(a[12]*0.1f) | ((unsigned)f2bf(a[13]*0.1f) << 16);
        o1.w = (unsigned)f2bf(a[14]*0.1f) | ((unsigned)f2bf(a[15]*0.1f) << 16);
        *(uint4*)((unsigned short*)&X2[row * 264 + cg * 16]) = o0;
        *(uint4*)((unsigned short*)&X2[row * 264 + cg * 16 + 8]) = o1;
    }
    __syncthreads();      // A buffers ready; K-loop is barrier-free from here

    f4v acc[4];           // [rt*2+f]
#pragma unroll
    for (int z = 0; z < 4; z++) acc[z] = (f4v){0.f, 0.f, 0.f, 0.f};

#pragma unroll
    for (int kc = 0; kc < 12; kc++) {
        const short* Ab = (kc < 4) ? Ah : (kc < 8) ? A1 : X2;
        int kl = (kc & 3) * 64;
#pragma unroll
        for (int ks = 0; ks < 2; ks++) {
            s8v a0 = *(const s8v*)(&Ab[l15 * 264 + kl + ks * 32 + quad * 8]);
            s8v a1 = *(const s8v*)(&Ab[(16 + l15) * 264 + kl + ks * 32 + quad * 8]);
#pragma unroll
            for (int f = 0; f < 2; f++) {
                s8v b = *(const s8v*)(Wt + ((kc * 2 + ks) * 16 + (w * 2 + f)) * 512 + lane * 8);
                acc[f]     = __builtin_amdgcn_mfma_f32_16x16x32_bf16(a0, b, acc[f], 0, 0, 0);
                acc[2 + f] = __builtin_amdgcn_mfma_f32_16x16x32_bf16(a1, b, acc[2 + f], 0, 0, 0);
            }
        }
    }

    // ---- epilogue: Euler update + readout partials ---------------------------
    float py[2][4][3] = {};
#pragma unroll
    for (int rt = 0; rt < 2; rt++) {
#pragma unroll
        for (int f = 0; f < 2; f++) {
            int col = w * 32 + f * 16 + l15;
            float cbv = cbl[col];
            float rw0 = rwl[col * 3], rw1 = rwl[col * 3 + 1], rw2 = rwl[col * 3 + 2];
#pragma unroll
            for (int r = 0; r < 4; r++) {
                int grow = m0 + rt * 16 + quad * 4 + r;
                float cval = acc[rt * 2 + f][r] + cbv;
                float hn = hdo[grow * 256 + col] + EPSC * tanhf(cval);
                hdo[grow * 256 + col] = hn;
                hbf[grow * 256 + col] = f2bf(hn);
                py[rt][r][0] += hn * rw0; py[rt][r][1] += hn * rw1; py[rt][r][2] += hn * rw2;
            }
        }
    }
    for (int off = 1; off < 16; off <<= 1)
        for (int rt = 0; rt < 2; rt++)
            for (int r = 0; r < 4; r++)
                for (int j = 0; j < 3; j++)
                    py[rt][r][j] += __shfl_xor(py[rt][r][j], off, 64);
    if (l15 == 0)
        for (int rt = 0; rt < 2; rt++)
            for (int r = 0; r < 4; r++)
                for (int j = 0; j < 3; j++)
                    yred[w][rt][quad][r][j] = py[rt][r][j];
    __syncthreads();
    if (w == 0 && l15 == 0) {
        for (int rt = 0; rt < 2; rt++) {
            for (int r = 0; r < 4; r++) {
                int grow = m0 + rt * 16 + quad * 4 + r;
                for (int j = 0; j < 3; j++) {
                    float yv = rb[j];
                    for (int ww = 0; ww < 8; ww++) yv += yred[ww][rt][quad][r][j];
                    yout[grow * 3 + j] = yv;
                    if (yfin) yfin[grow * 3 + j] = yv;
                }
            }
        }
    }
}

extern "C" void kernel_launch(void* const* d_in, const int* in_sizes, int n_in,
                              void* d_out, int out_size, void* d_ws, size_t ws_size,
                              hipStream_t stream) {
    const float* lm = (const float*)d_in[0];
    const float* ew = (const float*)d_in[1];
    const float* eb = (const float*)d_in[2];
    const float* rw = (const float*)d_in[3];
    const float* rb = (const float*)d_in[4];
    const float* cw = (const float*)d_in[5];
    const float* cb = (const float*)d_in[6];

    float* out = (float*)d_out;
    float* y_out = out;
    float* h_out = out + 24576;
    float* x_out = out + 24576 + 2097152;
    float* lp_out = x_out + 24576;

    char* ws = (char*)d_ws;
    int* nbr = (int*)ws;                       ws += NN * KNN * sizeof(int);
    float4* pos4 = (float4*)ws;                ws += NN * sizeof(float4);
    char* uni = ws;
    unsigned short* hbf = (unsigned short*)uni;
    unsigned short* x1  = hbf + NN * DH;
    unsigned short* Wt  = x1 + NN * DH;

    prep_pos<<<NN / 256, 256, 0, stream>>>(lm, pos4);
    knn_wave<<<NN / QPB, 1024, 0, stream>>>(lm, pos4, nbr);
    prep_wt<<<768, 256, 0, stream>>>(cw, Wt);
    emb_kernel<<<NN, 256, 0, stream>>>(lm, ew, eb, rw, rb, h_out, hbf, x_out);
    for (int t = 0; t < TSTEPS; t++) {
        agg_kernel<<<NN / 8, 256, 0, stream>>>(hbf, x1, nbr);
        gemm_step<<<NN / 32, 512, 0, stream>>>(hbf, x1, nbr, Wt, cb, rw, rb, h_out,
                                               lp_out + t * 24576,
                                               (t == TSTEPS - 1) ? y_out : nullptr);
    }
}

// Round 11
// 412.625 us; speedup vs baseline: 1.0135x; 1.0135x over previous
//
#include <hip/hip_runtime.h>
#include <float.h>
#include <math.h>

#define NN 8192
#define DH 256
#define KNN 10
#define TSTEPS 10
#define EPSC 0.1f
#define CTILE 1024          // candidates staged in LDS per tile
#define QPB 8               // queries per block (8 waves of 64)

typedef short s8v __attribute__((ext_vector_type(8)));
typedef float f4v __attribute__((ext_vector_type(4)));

__device__ __forceinline__ float bf2f(unsigned short u) {
    union { unsigned u; float f; } c; c.u = ((unsigned)u) << 16; return c.f;
}
__device__ __forceinline__ unsigned short f2bf(float f) {
    union { float f; unsigned u; } c; c.f = f;
    unsigned r = c.u + 0x7FFF + ((c.u >> 16) & 1);
    return (unsigned short)(r >> 16);
}

// -------- conv_ws [3][256][256] (k,n) -> FRAGMENT-MAJOR bf16 Wt ---------------
// frag = (kc*2+ks)*16 + nb. Lane layout matches the MFMA B operand exactly;
// a wave's B load = 1KB contiguous (fully coalesced), no LDS staging needed.
__global__ void prep_wt(const float* __restrict__ W, unsigned short* __restrict__ Wt) {
    int e = blockIdx.x * 256 + threadIdx.x;     // 768*256 = 196608
    int i8 = e & 7, lane = (e >> 3) & 63, nb = (e >> 9) & 15;
    int ks = (e >> 13) & 1, kc2 = (e >> 14) & 3, g = e >> 16;
    int quad = lane >> 4, l15 = lane & 15;
    int k = kc2 * 64 + ks * 32 + quad * 8 + i8;
    int n = nb * 16 + l15;
    Wt[e] = f2bf(W[g * 65536 + k * 256 + n]);
}

// ---------------- pos4[j] = {x, y, z, |p|^2} ----------------------------------
__global__ void prep_pos(const float* __restrict__ pos, float4* __restrict__ pos4) {
    int j = blockIdx.x * 256 + threadIdx.x;
    float x = pos[j * 3], y = pos[j * 3 + 1], z = pos[j * 3 + 2];
    float4 v; v.x = x; v.y = y; v.z = z; v.w = x * x + y * y + z * z;
    pos4[j] = v;
}

// ---------------- kNN: 1 wave/query, 8 queries/block, DPP-insert pops ---------
// R7-R9 structure (~55us at 1024-thr blocks, occ 62%). 512-thr blocks pack
// finer on the CU (8-wave granularity vs 16) -> more co-resident waves to
// hide the serial pop chains. Same math, same tie order (ascending j,
// strict '<').
__launch_bounds__(512)
__global__ void knn_wave(const float* __restrict__ pos, const float4* __restrict__ pos4,
                         int* __restrict__ nbr) {
    __shared__ float4 cand[CTILE];
    int tid = threadIdx.x;
    int wv = tid >> 6, lane = tid & 63;
    int i = blockIdx.x * QPB + wv;               // query for this wave
    float xi = pos[i * 3], yi = pos[i * 3 + 1], zi = pos[i * 3 + 2];
    float sqi = xi * xi + yi * yi + zi * zi;
    int igrp = i & ~63;                          // the only 64-group containing i

    float b  = FLT_MAX;                          // rank 'lane' distance
    int   ib = -1;                               // rank 'lane' index
    float thr = FLT_MAX;                         // 10th best (b at lane 9)

    for (int tile = 0; tile < NN / CTILE; ++tile) {
        __syncthreads();
        for (int t = tid; t < CTILE; t += 512) cand[t] = pos4[tile * CTILE + t];
        __syncthreads();
#pragma unroll 4
        for (int u = 0; u < CTILE / 64; ++u) {
            int jgrp = tile * CTILE + u * 64;
            float4 c = cand[u * 64 + lane];
            int j = jgrp + lane;
            float m = c.x * xi + c.y * yi + c.z * zi;
            float d = (sqi + c.w) - 2.0f * m;
            if (jgrp == igrp) {                  // wave-uniform branch
                if (j == i) d = FLT_MAX;         // self-exclusion, one batch only
            }
            unsigned long long mask = __ballot(d < thr);
            while (mask) {
                int l = __ffsll((unsigned long long)mask) - 1;
                mask &= mask - 1;
                float dc = __int_as_float(__builtin_amdgcn_readlane(__float_as_int(d), l));
                if (dc < thr) {                  // recheck vs updated threshold
                    int jc = __builtin_amdgcn_readlane(j, l);
                    // shift-down neighbors via DPP row_shr:1 (lane r <- r-1)
                    float bp = __int_as_float(__builtin_amdgcn_update_dpp(
                        0, __float_as_int(b), 0x111, 0xF, 0xF, true));
                    int ip = __builtin_amdgcn_update_dpp(0, ib, 0x111, 0xF, 0xF, true);
                    bool c0 = dc < b;                    // insert at/below my rank
                    bool cp = (lane != 0) && (dc < bp);  // insert strictly below
                    b  = c0 ? (cp ? bp : dc) : b;
                    ib = c0 ? (cp ? ip : jc) : ib;
                    thr = __int_as_float(__builtin_amdgcn_readlane(__float_as_int(b), 9));
                }
            }
        }
    }
    if (lane < KNN) nbr[i * KNN + lane] = ib;    // rank r already in lane r
}

// ---------------- h = lm@emb_w + emb_b ; x = h@rw + rb ------------------------
__global__ void emb_kernel(const float* __restrict__ lm, const float* __restrict__ ew,
                           const float* __restrict__ eb, const float* __restrict__ rw,
                           const float* __restrict__ rb,
                           float* __restrict__ hdo, unsigned short* __restrict__ hbf,
                           float* __restrict__ xout) {
    __shared__ float s0[4], s1[4], s2[4];
    int i = blockIdx.x, d = threadIdx.x;
    float a0 = lm[i * 3], a1 = lm[i * 3 + 1], a2 = lm[i * 3 + 2];
    float h = eb[d] + a0 * ew[d] + a1 * ew[256 + d] + a2 * ew[512 + d];
    hdo[i * 256 + d] = h;
    hbf[i * 256 + d] = f2bf(h);
    float p0 = h * rw[d * 3], p1 = h * rw[d * 3 + 1], p2 = h * rw[d * 3 + 2];
    for (int off = 32; off; off >>= 1) {
        p0 += __shfl_down(p0, off, 64);
        p1 += __shfl_down(p1, off, 64);
        p2 += __shfl_down(p2, off, 64);
    }
    int lane = d & 63, wid = d >> 6;
    if (lane == 0) { s0[wid] = p0; s1[wid] = p1; s2[wid] = p2; }
    __syncthreads();
    if (d == 0) {
        xout[i * 3 + 0] = s0[0] + s0[1] + s0[2] + s0[3] + rb[0];
        xout[i * 3 + 1] = s1[0] + s1[1] + s1[2] + s1[3] + rb[1];
        xout[i * 3 + 2] = s2[0] + s2[1] + s2[2] + s2[3] + rb[2];
    }
}

// ---------------- hop-1: x1[i] = 0.1 * sum_{j in nbr(i)} hbf[j] ---------------
__global__ void agg_kernel(const unsigned short* __restrict__ src,
                           unsigned short* __restrict__ dst,
                           const int* __restrict__ nbr) {
    int tid = threadIdx.x;
    int slot = tid >> 5, l32 = tid & 31;
    int node = blockIdx.x * 8 + slot;
    int d0 = l32 * 8;
    const int* nb = nbr + node * KNN;
    int j[KNN];
#pragma unroll
    for (int q = 0; q < KNN; q++) j[q] = nb[q];
    uint4 v[KNN];
#pragma unroll
    for (int q = 0; q < KNN; q++) v[q] = *(const uint4*)(src + j[q] * 256 + d0);
    float a[8];
#pragma unroll
    for (int e = 0; e < 8; e++) a[e] = 0.f;
#pragma unroll
    for (int q = 0; q < KNN; q++) {
        a[0] += bf2f((unsigned short)(v[q].x & 0xffff));
        a[1] += bf2f((unsigned short)(v[q].x >> 16));
        a[2] += bf2f((unsigned short)(v[q].y & 0xffff));
        a[3] += bf2f((unsigned short)(v[q].y >> 16));
        a[4] += bf2f((unsigned short)(v[q].z & 0xffff));
        a[5] += bf2f((unsigned short)(v[q].z >> 16));
        a[6] += bf2f((unsigned short)(v[q].w & 0xffff));
        a[7] += bf2f((unsigned short)(v[q].w >> 16));
    }
    uint4 o;
    o.x = (unsigned)f2bf(a[0]*0.1f) | ((unsigned)f2bf(a[1]*0.1f) << 16);
    o.y = (unsigned)f2bf(a[2]*0.1f) | ((unsigned)f2bf(a[3]*0.1f) << 16);
    o.z = (unsigned)f2bf(a[4]*0.1f) | ((unsigned)f2bf(a[5]*0.1f) << 16);
    o.w = (unsigned)f2bf(a[6]*0.1f) | ((unsigned)f2bf(a[7]*0.1f) << 16);
    *(uint4*)(dst + node * 256 + d0) = o;
}

// ------- fused: hop-2 gather + BARRIER-FREE-K GEMM + Euler + readout ----------
// M16 x N256, 256 threads = 4 waves; wave w owns 16 rows x 64 cols (acc[4]).
// LDS ~30KB -> 5 blocks/CU = 5 waves/SIMD (R9 was 4; R10's 2 waves/SIMD
// regressed: TLP > traffic on this kernel). B straight from fragment-major Wt
// (no LDS, no K-loop barriers; 2 barriers total). K order per output: kc 0..11,
// ks 0..1 ascending => bit-identical accumulation to R9.
__launch_bounds__(256, 4)
__global__ void gemm_step(unsigned short* hbf,
                          const unsigned short* __restrict__ x1,
                          const int* __restrict__ nbr,
                          const unsigned short* __restrict__ Wt,
                          const float* __restrict__ cb,
                          const float* __restrict__ rw, const float* __restrict__ rb,
                          float* hdo, float* __restrict__ yout, float* yfin) {
    __shared__ __align__(16) short Ah[16 * 264];
    __shared__ __align__(16) short A1[16 * 264];
    __shared__ __align__(16) short X2[16 * 264];
    __shared__ float rwl[768];
    __shared__ float cbl[256];
    __shared__ float yred[4][4][4][3];     // [wave][quad][r][xyz]

    int tid = threadIdx.x;
    int m0 = blockIdx.x * 16;
    for (int idx = tid; idx < 768; idx += 256) rwl[idx] = rw[idx];
    cbl[tid] = cb[tid];

    int w = tid >> 6, lane = tid & 63;
    int quad = lane >> 4, l15 = lane & 15;
    int row = tid >> 4, cg = tid & 15;            // stage: 16 rows x 16 thr, 16 shorts

    // ---- stage A for hop0 (hbf) and hop1 (x1): 2x uint4 per thread -----------
    {
        const unsigned short* hsrc = ((const unsigned short*)hbf) + (m0 + row) * 256 + cg * 16;
        uint4 va0 = *(const uint4*)(hsrc);
        uint4 va1 = *(const uint4*)(hsrc + 8);
        *(uint4*)((unsigned short*)&Ah[row * 264 + cg * 16]) = va0;
        *(uint4*)((unsigned short*)&Ah[row * 264 + cg * 16 + 8]) = va1;
        const unsigned short* xsrc = x1 + (m0 + row) * 256 + cg * 16;
        uint4 vb0 = *(const uint4*)(xsrc);
        uint4 vb1 = *(const uint4*)(xsrc + 8);
        *(uint4*)((unsigned short*)&A1[row * 264 + cg * 16]) = vb0;
        *(uint4*)((unsigned short*)&A1[row * 264 + cg * 16 + 8]) = vb1;
    }
    // ---- hop-2 gather: X2[row][:] = bf16(0.1 * sum x1[nbr[row]]) -------------
    {
        const int* nb = nbr + (m0 + row) * KNN;
        int j[KNN];
#pragma unroll
        for (int q = 0; q < KNN; q++) j[q] = nb[q];
        float a[16];
#pragma unroll
        for (int e = 0; e < 16; e++) a[e] = 0.f;
#pragma unroll
        for (int q = 0; q < KNN; q++) {
            const unsigned short* p = x1 + j[q] * 256 + cg * 16;
            uint4 v0 = *(const uint4*)(p);
            uint4 v1 = *(const uint4*)(p + 8);
            a[0]  += bf2f((unsigned short)(v0.x & 0xffff));
            a[1]  += bf2f((unsigned short)(v0.x >> 16));
            a[2]  += bf2f((unsigned short)(v0.y & 0xffff));
            a[3]  += bf2f((unsigned short)(v0.y >> 16));
            a[4]  += bf2f((unsigned short)(v0.z & 0xffff));
            a[5]  += bf2f((unsigned short)(v0.z >> 16));
            a[6]  += bf2f((unsigned short)(v0.w & 0xffff));
            a[7]  += bf2f((unsigned short)(v0.w >> 16));
            a[8]  += bf2f((unsigned short)(v1.x & 0xffff));
            a[9]  += bf2f((unsigned short)(v1.x >> 16));
            a[10] += bf2f((unsigned short)(v1.y & 0xffff));
            a[11] += bf2f((unsigned short)(v1.y >> 16));
            a[12] += bf2f((unsigned short)(v1.z & 0xffff));
            a[13] += bf2f((unsigned short)(v1.z >> 16));
            a[14] += bf2f((unsigned short)(v1.w & 0xffff));
            a[15] += bf2f((unsigned short)(v1.w >> 16));
        }
        uint4 o0, o1;
        o0.x = (unsigned)f2bf(a[0]*0.1f)  | ((unsigned)f2bf(a[1]*0.1f)  << 16);
        o0.y = (unsigned)f2bf(a[2]*0.1f)  | ((unsigned)f2bf(a[3]*0.1f)  << 16);
        o0.z = (unsigned)f2bf(a[4]*0.1f)  | ((unsigned)f2bf(a[5]*0.1f)  << 16);
        o0.w = (unsigned)f2bf(a[6]*0.1f)  | ((unsigned)f2bf(a[7]*0.1f)  << 16);
        o1.x = (unsigned)f2bf(a[8]*0.1f)  | ((unsigned)f2bf(a[9]*0.1f)  << 16);
        o1.y = (unsigned)f2bf(a[10]*0.1f) | ((unsigned)f2bf(a[11]*0.1f) << 16);
        o1.z = (unsigned)f2bf(a[12]*0.1f) | ((unsigned)f2bf(a[13]*0.1f) << 16);
        o1.w = (unsigned)f2bf(a[14]*0.1f) | ((unsigned)f2bf(a[15]*0.1f) << 16);
        *(uint4*)((unsigned short*)&X2[row * 264 + cg * 16]) = o0;
        *(uint4*)((unsigned short*)&X2[row * 264 + cg * 16 + 8]) = o1;
    }
    __syncthreads();      // A buffers ready; K-loop is barrier-free from here

    f4v acc[4];
#pragma unroll
    for (int z = 0; z < 4; z++) acc[z] = (f4v){0.f, 0.f, 0.f, 0.f};

#pragma unroll
    for (int kc = 0; kc < 12; kc++) {
        const short* Ab = (kc < 4) ? Ah : (kc < 8) ? A1 : X2;
        int kl = (kc & 3) * 64;
#pragma unroll
        for (int ks = 0; ks < 2; ks++) {
            s8v a = *(const s8v*)(&Ab[l15 * 264 + kl + ks * 32 + quad * 8]);
#pragma unroll
            for (int f = 0; f < 4; f++) {
                // fragment-major B: one coalesced 1KB wave load
                s8v b = *(const s8v*)(Wt + ((kc * 2 + ks) * 16 + (w * 4 + f)) * 512 + lane * 8);
                acc[f] = __builtin_amdgcn_mfma_f32_16x16x32_bf16(a, b, acc[f], 0, 0, 0);
            }
        }
    }

    // ---- epilogue: Euler update + readout partials ---------------------------
    float py[4][3] = {};
#pragma unroll
    for (int f = 0; f < 4; f++) {
        int col = w * 64 + f * 16 + l15;
        float cbv = cbl[col];
        float rw0 = rwl[col * 3], rw1 = rwl[col * 3 + 1], rw2 = rwl[col * 3 + 2];
#pragma unroll
        for (int r = 0; r < 4; r++) {
            int grow = m0 + quad * 4 + r;
            float cval = acc[f][r] + cbv;
            float hn = hdo[grow * 256 + col] + EPSC * tanhf(cval);
            hdo[grow * 256 + col] = hn;
            hbf[grow * 256 + col] = f2bf(hn);
            py[r][0] += hn * rw0; py[r][1] += hn * rw1; py[r][2] += hn * rw2;
        }
    }
    for (int off = 1; off < 16; off <<= 1)
        for (int r = 0; r < 4; r++)
            for (int j = 0; j < 3; j++)
                py[r][j] += __shfl_xor(py[r][j], off, 64);
    if (l15 == 0)
        for (int r = 0; r < 4; r++)
            for (int j = 0; j < 3; j++)
                yred[w][quad][r][j] = py[r][j];
    __syncthreads();
    if (w == 0 && l15 == 0) {
        for (int r = 0; r < 4; r++) {
            int grow = m0 + quad * 4 + r;
            for (int j = 0; j < 3; j++) {
                float yv = rb[j];
                for (int ww = 0; ww < 4; ww++) yv += yred[ww][quad][r][j];
                yout[grow * 3 + j] = yv;
                if (yfin) yfin[grow * 3 + j] = yv;
            }
        }
    }
}

extern "C" void kernel_launch(void* const* d_in, const int* in_sizes, int n_in,
                              void* d_out, int out_size, void* d_ws, size_t ws_size,
                              hipStream_t stream) {
    const float* lm = (const float*)d_in[0];
    const float* ew = (const float*)d_in[1];
    const float* eb = (const float*)d_in[2];
    const float* rw = (const float*)d_in[3];
    const float* rb = (const float*)d_in[4];
    const float* cw = (const float*)d_in[5];
    const float* cb = (const float*)d_in[6];

    float* out = (float*)d_out;
    float* y_out = out;
    float* h_out = out + 24576;
    float* x_out = out + 24576 + 2097152;
    float* lp_out = x_out + 24576;

    char* ws = (char*)d_ws;
    int* nbr = (int*)ws;                       ws += NN * KNN * sizeof(int);
    float4* pos4 = (float4*)ws;                ws += NN * sizeof(float4);
    char* uni = ws;
    unsigned short* hbf = (unsigned short*)uni;
    unsigned short* x1  = hbf + NN * DH;
    unsigned short* Wt  = x1 + NN * DH;

    prep_pos<<<NN / 256, 256, 0, stream>>>(lm, pos4);
    knn_wave<<<NN / QPB, 512, 0, stream>>>(lm, pos4, nbr);
    prep_wt<<<768, 256, 0, stream>>>(cw, Wt);
    emb_kernel<<<NN, 256, 0, stream>>>(lm, ew, eb, rw, rb, h_out, hbf, x_out);
    for (int t = 0; t < TSTEPS; t++) {
        agg_kernel<<<NN / 8, 256, 0, stream>>>(hbf, x1, nbr);
        gemm_step<<<NN / 16, 256, 0, stream>>>(hbf, x1, nbr, Wt, cb, rw, rb, h_out,
                                               lp_out + t * 24576,
                                               (t == TSTEPS - 1) ? y_out : nullptr);
    }
}

// Round 13
// 395.533 us; speedup vs baseline: 1.0573x; 1.0432x over previous
//
#include <hip/hip_runtime.h>
#include <float.h>
#include <math.h>

#define NN 8192
#define DH 256
#define KNN 10
#define TSTEPS 10
#define EPSC 0.1f
#define CTILE 1024          // candidates per half-wave per tile-pair
#define QPB 8               // queries per block (8 queries x 2 half-waves)

typedef short s8v __attribute__((ext_vector_type(8)));
typedef float f4v __attribute__((ext_vector_type(4)));

__device__ __forceinline__ float bf2f(unsigned short u) {
    union { unsigned u; float f; } c; c.u = ((unsigned)u) << 16; return c.f;
}
__device__ __forceinline__ unsigned short f2bf(float f) {
    union { float f; unsigned u; } c; c.f = f;
    unsigned r = c.u + 0x7FFF + ((c.u >> 16) & 1);
    return (unsigned short)(r >> 16);
}

// -------- conv_ws [3][256][256] (k,n) -> FRAGMENT-MAJOR bf16 Wt ---------------
// frag = (kc*2+ks)*16 + nb. Lane layout matches the MFMA B operand exactly;
// a wave's B load = 1KB contiguous (fully coalesced), no LDS staging needed.
__global__ void prep_wt(const float* __restrict__ W, unsigned short* __restrict__ Wt) {
    int e = blockIdx.x * 256 + threadIdx.x;     // 768*256 = 196608
    int i8 = e & 7, lane = (e >> 3) & 63, nb = (e >> 9) & 15;
    int ks = (e >> 13) & 1, kc2 = (e >> 14) & 3, g = e >> 16;
    int quad = lane >> 4, l15 = lane & 15;
    int k = kc2 * 64 + ks * 32 + quad * 8 + i8;
    int n = nb * 16 + l15;
    Wt[e] = f2bf(W[g * 65536 + k * 256 + n]);
}

// ---------------- pos4[j] = {x, y, z, |p|^2} ----------------------------------
__global__ void prep_pos(const float* __restrict__ pos, float4* __restrict__ pos4) {
    int j = blockIdx.x * 256 + threadIdx.x;
    float x = pos[j * 3], y = pos[j * 3 + 1], z = pos[j * 3 + 2];
    float4 v; v.x = x; v.y = y; v.z = z; v.w = x * x + y * y + z * z;
    pos4[j] = v;
}

// ---------------- kNN: 2 half-waves/query, DPP-insert pops, LDS merge ---------
// Each query is scanned by TWO waves (half 0: j<4096, half 1: j>=4096), each
// keeping a rank-in-lane distributed top-10 with the cheap DPP insert (R7).
// Serial pop chain per wave halves (~40 vs ~77 pops) — R2 showed the split
// works; R3's regression was its 50-VALU replicated insert, not the split.
// Tile-pairs (t, t+4) stage together (32KB LDS) so halves never idle.
// Merge: half1 publishes its sorted 10 via LDS; half0 inserts them (uniform
// candidates). half-0 indices < half-1 indices + strict '<' => jax tie order.
__launch_bounds__(1024)
__global__ void knn_wave(const float* __restrict__ pos, const float4* __restrict__ pos4,
                         int* __restrict__ nbr) {
    __shared__ float4 cand[2 * CTILE];
    __shared__ float md[QPB][KNN];
    __shared__ int   mj[QPB][KNN];
    int tid = threadIdx.x;
    int wv = tid >> 7;                 // query slot 0..7
    int half = (tid >> 6) & 1;         // candidate half
    int lane = tid & 63;
    int i = blockIdx.x * QPB + wv;
    float xi = pos[i * 3], yi = pos[i * 3 + 1], zi = pos[i * 3 + 2];
    float sqi = xi * xi + yi * yi + zi * zi;
    int igrp = i & ~63;                // the only 64-group containing i

    float b  = FLT_MAX;                // rank 'lane' distance
    int   ib = -1;                     // rank 'lane' index
    float thr = FLT_MAX;               // 10th best (b at lane 9)

    for (int tp = 0; tp < 4; ++tp) {
        __syncthreads();
        cand[tid]        = pos4[tp * CTILE + tid];           // tiles 0..3
        cand[1024 + tid] = pos4[(tp + 4) * CTILE + tid];     // tiles 4..7
        __syncthreads();
        int jbase = (tp + half * 4) * CTILE;
        const float4* cbase = cand + half * CTILE;
#pragma unroll 4
        for (int u = 0; u < CTILE / 64; ++u) {
            int jgrp = jbase + u * 64;
            float4 c = cbase[u * 64 + lane];
            int j = jgrp + lane;
            float m = c.x * xi + c.y * yi + c.z * zi;
            float d = (sqi + c.w) - 2.0f * m;
            if (jgrp == igrp) {                  // wave-uniform branch
                if (j == i) d = FLT_MAX;         // self-exclusion, one batch only
            }
            unsigned long long mask = __ballot(d < thr);
            while (mask) {
                int l = __ffsll((unsigned long long)mask) - 1;
                mask &= mask - 1;
                float dc = __int_as_float(__builtin_amdgcn_readlane(__float_as_int(d), l));
                if (dc < thr) {                  // recheck vs updated threshold
                    int jc = __builtin_amdgcn_readlane(j, l);
                    // shift-down neighbors via DPP row_shr:1 (lane r <- r-1)
                    float bp = __int_as_float(__builtin_amdgcn_update_dpp(
                        0, __float_as_int(b), 0x111, 0xF, 0xF, true));
                    int ip = __builtin_amdgcn_update_dpp(0, ib, 0x111, 0xF, 0xF, true);
                    bool c0 = dc < b;                    // insert at/below my rank
                    bool cp = (lane != 0) && (dc < bp);  // insert strictly below
                    b  = c0 ? (cp ? bp : dc) : b;
                    ib = c0 ? (cp ? ip : jc) : ib;
                    thr = __int_as_float(__builtin_amdgcn_readlane(__float_as_int(b), 9));
                }
            }
        }
    }

    // ---- merge: half1 -> LDS, half0 inserts (ascending rank = ascending j per
    // original scan order within half; half-0 j < half-1 j on ties) -----------
    __syncthreads();
    if (half == 1 && lane < KNN) { md[wv][lane] = b; mj[wv][lane] = ib; }
    __syncthreads();
    if (half == 0) {
        for (int q = 0; q < KNN; q++) {
            float dq = md[wv][q];                // uniform LDS broadcast
            int   jq = mj[wv][q];
            if (dq < thr) {
                float bp = __int_as_float(__builtin_amdgcn_update_dpp(
                    0, __float_as_int(b), 0x111, 0xF, 0xF, true));
                int ip = __builtin_amdgcn_update_dpp(0, ib, 0x111, 0xF, 0xF, true);
                bool c0 = dq < b;
                bool cp = (lane != 0) && (dq < bp);
                b  = c0 ? (cp ? bp : dq) : b;
                ib = c0 ? (cp ? ip : jq) : ib;
                thr = __int_as_float(__builtin_amdgcn_readlane(__float_as_int(b), 9));
            }
        }
        if (lane < KNN) nbr[i * KNN + lane] = ib;    // rank r in lane r
    }
}

// ---------------- h = lm@emb_w + emb_b ; x = h@rw + rb ------------------------
__global__ void emb_kernel(const float* __restrict__ lm, const float* __restrict__ ew,
                           const float* __restrict__ eb, const float* __restrict__ rw,
                           const float* __restrict__ rb,
                           float* __restrict__ hdo, unsigned short* __restrict__ hbf,
                           float* __restrict__ xout) {
    __shared__ float s0[4], s1[4], s2[4];
    int i = blockIdx.x, d = threadIdx.x;
    float a0 = lm[i * 3], a1 = lm[i * 3 + 1], a2 = lm[i * 3 + 2];
    float h = eb[d] + a0 * ew[d] + a1 * ew[256 + d] + a2 * ew[512 + d];
    hdo[i * 256 + d] = h;
    hbf[i * 256 + d] = f2bf(h);
    float p0 = h * rw[d * 3], p1 = h * rw[d * 3 + 1], p2 = h * rw[d * 3 + 2];
    for (int off = 32; off; off >>= 1) {
        p0 += __shfl_down(p0, off, 64);
        p1 += __shfl_down(p1, off, 64);
        p2 += __shfl_down(p2, off, 64);
    }
    int lane = d & 63, wid = d >> 6;
    if (lane == 0) { s0[wid] = p0; s1[wid] = p1; s2[wid] = p2; }
    __syncthreads();
    if (d == 0) {
        xout[i * 3 + 0] = s0[0] + s0[1] + s0[2] + s0[3] + rb[0];
        xout[i * 3 + 1] = s1[0] + s1[1] + s1[2] + s1[3] + rb[1];
        xout[i * 3 + 2] = s2[0] + s2[1] + s2[2] + s2[3] + rb[2];
    }
}

// ---------------- hop-1: x1[i] = 0.1 * sum_{j in nbr(i)} hbf[j] ---------------
__global__ void agg_kernel(const unsigned short* __restrict__ src,
                           unsigned short* __restrict__ dst,
                           const int* __restrict__ nbr) {
    int tid = threadIdx.x;
    int slot = tid >> 5, l32 = tid & 31;
    int node = blockIdx.x * 8 + slot;
    int d0 = l32 * 8;
    const int* nb = nbr + node * KNN;
    int j[KNN];
#pragma unroll
    for (int q = 0; q < KNN; q++) j[q] = nb[q];
    uint4 v[KNN];
#pragma unroll
    for (int q = 0; q < KNN; q++) v[q] = *(const uint4*)(src + j[q] * 256 + d0);
    float a[8];
#pragma unroll
    for (int e = 0; e < 8; e++) a[e] = 0.f;
#pragma unroll
    for (int q = 0; q < KNN; q++) {
        a[0] += bf2f((unsigned short)(v[q].x & 0xffff));
        a[1] += bf2f((unsigned short)(v[q].x >> 16));
        a[2] += bf2f((unsigned short)(v[q].y & 0xffff));
        a[3] += bf2f((unsigned short)(v[q].y >> 16));
        a[4] += bf2f((unsigned short)(v[q].z & 0xffff));
        a[5] += bf2f((unsigned short)(v[q].z >> 16));
        a[6] += bf2f((unsigned short)(v[q].w & 0xffff));
        a[7] += bf2f((unsigned short)(v[q].w >> 16));
    }
    uint4 o;
    o.x = (unsigned)f2bf(a[0]*0.1f) | ((unsigned)f2bf(a[1]*0.1f) << 16);
    o.y = (unsigned)f2bf(a[2]*0.1f) | ((unsigned)f2bf(a[3]*0.1f) << 16);
    o.z = (unsigned)f2bf(a[4]*0.1f) | ((unsigned)f2bf(a[5]*0.1f) << 16);
    o.w = (unsigned)f2bf(a[6]*0.1f) | ((unsigned)f2bf(a[7]*0.1f) << 16);
    *(uint4*)(dst + node * 256 + d0) = o;
}

// ------- fused: hop-2 gather + BARRIER-FREE-K GEMM + Euler + readout ----------
// R9 exact (measured ~380us composite): M16 x N256, 512 threads (8 waves),
// grid 512 = 2 blocks/CU = 4 waves/SIMD. B from fragment-major Wt (coalesced,
// no LDS, no K-loop barriers; 2 barriers total). R10/R11 lesson: occupancy =
// min(grid, LDS, VGPR) — this config is the local optimum from both sides.
__launch_bounds__(512, 4)
__global__ void gemm_step(unsigned short* hbf,
                          const unsigned short* __restrict__ x1,
                          const int* __restrict__ nbr,
                          const unsigned short* __restrict__ Wt,
                          const float* __restrict__ cb,
                          const float* __restrict__ rw, const float* __restrict__ rb,
                          float* hdo, float* __restrict__ yout, float* yfin) {
    __shared__ __align__(16) short Ah[16 * 264];
    __shared__ __align__(16) short A1[16 * 264];
    __shared__ __align__(16) short X2[16 * 264];
    __shared__ float rwl[768];
    __shared__ float cbl[256];
    __shared__ float yred[8][4][4][3];     // [wave][quad][r][xyz]

    int tid = threadIdx.x;
    int m0 = blockIdx.x * 16;
    for (int idx = tid; idx < 768; idx += 512) rwl[idx] = rw[idx];
    if (tid < 256) cbl[tid] = cb[tid];

    int w = tid >> 6, lane = tid & 63;
    int quad = lane >> 4, l15 = lane & 15;
    int row = tid >> 5, cg = tid & 31;            // stage coords: 16 rows x 32 thr

    // ---- stage A for hop0 (hbf) and hop1 (x1) --------------------------------
    {
        uint4 va = *(const uint4*)(((const unsigned short*)hbf) + (m0 + row) * 256 + cg * 8);
        *(uint4*)((unsigned short*)&Ah[row * 264 + cg * 8]) = va;
        uint4 vb = *(const uint4*)(x1 + (m0 + row) * 256 + cg * 8);
        *(uint4*)((unsigned short*)&A1[row * 264 + cg * 8]) = vb;
    }
    // ---- hop-2 gather: X2[row][:] = bf16(0.1 * sum x1[nbr[row]]) -------------
    {
        const int* nb = nbr + (m0 + row) * KNN;
        int j[KNN];
#pragma unroll
        for (int q = 0; q < KNN; q++) j[q] = nb[q];
        float a[8];
#pragma unroll
        for (int e = 0; e < 8; e++) a[e] = 0.f;
#pragma unroll
        for (int q = 0; q < KNN; q++) {
            uint4 v = *(const uint4*)(x1 + j[q] * 256 + cg * 8);
            a[0] += bf2f((unsigned short)(v.x & 0xffff));
            a[1] += bf2f((unsigned short)(v.x >> 16));
            a[2] += bf2f((unsigned short)(v.y & 0xffff));
            a[3] += bf2f((unsigned short)(v.y >> 16));
            a[4] += bf2f((unsigned short)(v.z & 0xffff));
            a[5] += bf2f((unsigned short)(v.z >> 16));
            a[6] += bf2f((unsigned short)(v.w & 0xffff));
            a[7] += bf2f((unsigned short)(v.w >> 16));
        }
        uint4 o;
        o.x = (unsigned)f2bf(a[0]*0.1f) | ((unsigned)f2bf(a[1]*0.1f) << 16);
        o.y = (unsigned)f2bf(a[2]*0.1f) | ((unsigned)f2bf(a[3]*0.1f) << 16);
        o.z = (unsigned)f2bf(a[4]*0.1f) | ((unsigned)f2bf(a[5]*0.1f) << 16);
        o.w = (unsigned)f2bf(a[6]*0.1f) | ((unsigned)f2bf(a[7]*0.1f) << 16);
        *(uint4*)((unsigned short*)&X2[row * 264 + cg * 8]) = o;
    }
    __syncthreads();      // A buffers ready; K-loop is barrier-free from here

    f4v acc[2];
    acc[0] = (f4v){0.f, 0.f, 0.f, 0.f};
    acc[1] = (f4v){0.f, 0.f, 0.f, 0.f};

#pragma unroll
    for (int kc = 0; kc < 12; kc++) {
        const short* Ab = (kc < 4) ? Ah : (kc < 8) ? A1 : X2;
        int kl = (kc & 3) * 64;
#pragma unroll
        for (int ks = 0; ks < 2; ks++) {
            s8v a = *(const s8v*)(&Ab[l15 * 264 + kl + ks * 32 + quad * 8]);
#pragma unroll
            for (int f = 0; f < 2; f++) {
                // fragment-major B: one coalesced 1KB wave load
                s8v b = *(const s8v*)(Wt + ((kc * 2 + ks) * 16 + (w * 2 + f)) * 512 + lane * 8);
                acc[f] = __builtin_amdgcn_mfma_f32_16x16x32_bf16(a, b, acc[f], 0, 0, 0);
            }
        }
    }

    // ---- epilogue: Euler update + readout partials ---------------------------
    float py[4][3] = {};
#pragma unroll
    for (int f = 0; f < 2; f++) {
        int col = w * 32 + f * 16 + l15;
        float cbv = cbl[col];
        float rw0 = rwl[col * 3], rw1 = rwl[col * 3 + 1], rw2 = rwl[col * 3 + 2];
#pragma unroll
        for (int r = 0; r < 4; r++) {
            int grow = m0 + quad * 4 + r;
            float cval = acc[f][r] + cbv;
            float hn = hdo[grow * 256 + col] + EPSC * tanhf(cval);
            hdo[grow * 256 + col] = hn;
            hbf[grow * 256 + col] = f2bf(hn);
            py[r][0] += hn * rw0; py[r][1] += hn * rw1; py[r][2] += hn * rw2;
        }
    }
    for (int off = 1; off < 16; off <<= 1)
        for (int r = 0; r < 4; r++)
            for (int j = 0; j < 3; j++)
                py[r][j] += __shfl_xor(py[r][j], off, 64);
    if (l15 == 0)
        for (int r = 0; r < 4; r++)
            for (int j = 0; j < 3; j++)
                yred[w][quad][r][j] = py[r][j];
    __syncthreads();
    if (w == 0 && l15 == 0) {
        for (int r = 0; r < 4; r++) {
            int grow = m0 + quad * 4 + r;
            for (int j = 0; j < 3; j++) {
                float yv = rb[j];
                for (int ww = 0; ww < 8; ww++) yv += yred[ww][quad][r][j];
                yout[grow * 3 + j] = yv;
                if (yfin) yfin[grow * 3 + j] = yv;
            }
        }
    }
}

extern "C" void kernel_launch(void* const* d_in, const int* in_sizes, int n_in,
                              void* d_out, int out_size, void* d_ws, size_t ws_size,
                              hipStream_t stream) {
    const float* lm = (const float*)d_in[0];
    const float* ew = (const float*)d_in[1];
    const float* eb = (const float*)d_in[2];
    const float* rw = (const float*)d_in[3];
    const float* rb = (const float*)d_in[4];
    const float* cw = (const float*)d_in[5];
    const float* cb = (const float*)d_in[6];

    float* out = (float*)d_out;
    float* y_out = out;
    float* h_out = out + 24576;
    float* x_out = out + 24576 + 2097152;
    float* lp_out = x_out + 24576;

    char* ws = (char*)d_ws;
    int* nbr = (int*)ws;                       ws += NN * KNN * sizeof(int);
    float4* pos4 = (float4*)ws;                ws += NN * sizeof(float4);
    char* uni = ws;
    unsigned short* hbf = (unsigned short*)uni;
    unsigned short* x1  = hbf + NN * DH;
    unsigned short* Wt  = x1 + NN * DH;

    prep_pos<<<NN / 256, 256, 0, stream>>>(lm, pos4);
    knn_wave<<<NN / QPB, 1024, 0, stream>>>(lm, pos4, nbr);
    prep_wt<<<768, 256, 0, stream>>>(cw, Wt);
    emb_kernel<<<NN, 256, 0, stream>>>(lm, ew, eb, rw, rb, h_out, hbf, x_out);
    for (int t = 0; t < TSTEPS; t++) {
        agg_kernel<<<NN / 8, 256, 0, stream>>>(hbf, x1, nbr);
        gemm_step<<<NN / 16, 512, 0, stream>>>(hbf, x1, nbr, Wt, cb, rw, rb, h_out,
                                               lp_out + t * 24576,
                                               (t == TSTEPS - 1) ? y_out : nullptr);
    }
}

// Round 14
// 379.761 us; speedup vs baseline: 1.1012x; 1.0415x over previous
//
#include <hip/hip_runtime.h>
#include <float.h>
#include <math.h>

#define NN 8192
#define DH 256
#define KNN 10
#define TSTEPS 10
#define EPSC 0.1f
#define CTILE 1024          // candidates staged in LDS per tile
#define QPB 16              // queries per block (16 waves of 64)

typedef short s8v __attribute__((ext_vector_type(8)));
typedef float f4v __attribute__((ext_vector_type(4)));

__device__ __forceinline__ float bf2f(unsigned short u) {
    union { unsigned u; float f; } c; c.u = ((unsigned)u) << 16; return c.f;
}
__device__ __forceinline__ unsigned short f2bf(float f) {
    union { float f; unsigned u; } c; c.f = f;
    unsigned r = c.u + 0x7FFF + ((c.u >> 16) & 1);
    return (unsigned short)(r >> 16);
}

// -------- conv_ws [3][256][256] (k,n) -> FRAGMENT-MAJOR bf16 Wt ---------------
// frag = (kc*2+ks)*16 + nb. Lane layout matches the MFMA B operand exactly;
// a wave's B load = 1KB contiguous (fully coalesced), no LDS staging needed.
__global__ void prep_wt(const float* __restrict__ W, unsigned short* __restrict__ Wt) {
    int e = blockIdx.x * 256 + threadIdx.x;     // 768*256 = 196608
    int i8 = e & 7, lane = (e >> 3) & 63, nb = (e >> 9) & 15;
    int ks = (e >> 13) & 1, kc2 = (e >> 14) & 3, g = e >> 16;
    int quad = lane >> 4, l15 = lane & 15;
    int k = kc2 * 64 + ks * 32 + quad * 8 + i8;
    int n = nb * 16 + l15;
    Wt[e] = f2bf(W[g * 65536 + k * 256 + n]);
}

// ---------------- pos4[j] = {x, y, z, |p|^2} ----------------------------------
__global__ void prep_pos(const float* __restrict__ pos, float4* __restrict__ pos4) {
    int j = blockIdx.x * 256 + threadIdx.x;
    float x = pos[j * 3], y = pos[j * 3 + 1], z = pos[j * 3 + 2];
    float4 v; v.x = x; v.y = y; v.z = z; v.w = x * x + y * y + z * z;
    pos4[j] = v;
}

// ---------------- kNN: 1 wave/query, 16 queries/block, DPP-insert pops --------
// R7 structure (~55us) + batch-level threshold update: thr is refreshed ONCE
// per 64-candidate batch (after the ballot mask drains) instead of per pop,
// and the per-pop recheck is dropped. Correct because (1) inserting a non-
// qualifying candidate into the sorted rank-in-lane list is a no-op (strict
// '<' fails at every rank), and (2) batch-level thr >= live b9 always, so the
// ballot over-admits but never skips a qualifier. Pop dep-chain shrinks from
// ~10 ops (serialized through thr readlane) to ~6 (b/ib DPP chain only).
// R13 lesson: do NOT split the scan across waves — inserts ~ 10*ln(N/10),
// nearly scan-length-independent, so splitting doubles total work.
__launch_bounds__(1024)
__global__ void knn_wave(const float* __restrict__ pos, const float4* __restrict__ pos4,
                         int* __restrict__ nbr) {
    __shared__ float4 cand[CTILE];
    int tid = threadIdx.x;
    int wv = tid >> 6, lane = tid & 63;
    int i = blockIdx.x * QPB + wv;               // query for this wave
    float xi = pos[i * 3], yi = pos[i * 3 + 1], zi = pos[i * 3 + 2];
    float sqi = xi * xi + yi * yi + zi * zi;
    int igrp = i & ~63;                          // the only 64-group containing i

    float b  = FLT_MAX;                          // rank 'lane' distance
    int   ib = -1;                               // rank 'lane' index
    float thr = FLT_MAX;                         // batch-level 10th best bound

    for (int tile = 0; tile < NN / CTILE; ++tile) {
        __syncthreads();
        cand[tid] = pos4[tile * CTILE + tid];    // 1024 threads, 1 float4 each
        __syncthreads();
#pragma unroll 4
        for (int u = 0; u < CTILE / 64; ++u) {
            int jgrp = tile * CTILE + u * 64;
            float4 c = cand[u * 64 + lane];
            int j = jgrp + lane;
            float m = c.x * xi + c.y * yi + c.z * zi;
            float d = (sqi + c.w) - 2.0f * m;
            if (jgrp == igrp) {                  // wave-uniform branch
                if (j == i) d = FLT_MAX;         // self-exclusion, one batch only
            }
            unsigned long long mask = __ballot(d < thr);
            if (mask) {
                do {
                    int l = __ffsll((unsigned long long)mask) - 1;
                    mask &= mask - 1;
                    float dc = __int_as_float(__builtin_amdgcn_readlane(__float_as_int(d), l));
                    int jc = __builtin_amdgcn_readlane(j, l);
                    // shift-down neighbors via DPP row_shr:1 (lane r <- r-1)
                    float bp = __int_as_float(__builtin_amdgcn_update_dpp(
                        0, __float_as_int(b), 0x111, 0xF, 0xF, true));
                    int ip = __builtin_amdgcn_update_dpp(0, ib, 0x111, 0xF, 0xF, true);
                    bool c0 = dc < b;                    // insert at/below my rank
                    bool cp = (lane != 0) && (dc < bp);  // insert strictly below
                    b  = c0 ? (cp ? bp : dc) : b;
                    ib = c0 ? (cp ? ip : jc) : ib;
                } while (mask);
                thr = __int_as_float(__builtin_amdgcn_readlane(__float_as_int(b), 9));
            }
        }
    }
    if (lane < KNN) nbr[i * KNN + lane] = ib;    // rank r already in lane r
}

// ---------------- h = lm@emb_w + emb_b ; x = h@rw + rb ------------------------
__global__ void emb_kernel(const float* __restrict__ lm, const float* __restrict__ ew,
                           const float* __restrict__ eb, const float* __restrict__ rw,
                           const float* __restrict__ rb,
                           float* __restrict__ hdo, unsigned short* __restrict__ hbf,
                           float* __restrict__ xout) {
    __shared__ float s0[4], s1[4], s2[4];
    int i = blockIdx.x, d = threadIdx.x;
    float a0 = lm[i * 3], a1 = lm[i * 3 + 1], a2 = lm[i * 3 + 2];
    float h = eb[d] + a0 * ew[d] + a1 * ew[256 + d] + a2 * ew[512 + d];
    hdo[i * 256 + d] = h;
    hbf[i * 256 + d] = f2bf(h);
    float p0 = h * rw[d * 3], p1 = h * rw[d * 3 + 1], p2 = h * rw[d * 3 + 2];
    for (int off = 32; off; off >>= 1) {
        p0 += __shfl_down(p0, off, 64);
        p1 += __shfl_down(p1, off, 64);
        p2 += __shfl_down(p2, off, 64);
    }
    int lane = d & 63, wid = d >> 6;
    if (lane == 0) { s0[wid] = p0; s1[wid] = p1; s2[wid] = p2; }
    __syncthreads();
    if (d == 0) {
        xout[i * 3 + 0] = s0[0] + s0[1] + s0[2] + s0[3] + rb[0];
        xout[i * 3 + 1] = s1[0] + s1[1] + s1[2] + s1[3] + rb[1];
        xout[i * 3 + 2] = s2[0] + s2[1] + s2[2] + s2[3] + rb[2];
    }
}

// ---------------- hop-1: x1[i] = 0.1 * sum_{j in nbr(i)} hbf[j] ---------------
__global__ void agg_kernel(const unsigned short* __restrict__ src,
                           unsigned short* __restrict__ dst,
                           const int* __restrict__ nbr) {
    int tid = threadIdx.x;
    int slot = tid >> 5, l32 = tid & 31;
    int node = blockIdx.x * 8 + slot;
    int d0 = l32 * 8;
    const int* nb = nbr + node * KNN;
    int j[KNN];
#pragma unroll
    for (int q = 0; q < KNN; q++) j[q] = nb[q];
    uint4 v[KNN];
#pragma unroll
    for (int q = 0; q < KNN; q++) v[q] = *(const uint4*)(src + j[q] * 256 + d0);
    float a[8];
#pragma unroll
    for (int e = 0; e < 8; e++) a[e] = 0.f;
#pragma unroll
    for (int q = 0; q < KNN; q++) {
        a[0] += bf2f((unsigned short)(v[q].x & 0xffff));
        a[1] += bf2f((unsigned short)(v[q].x >> 16));
        a[2] += bf2f((unsigned short)(v[q].y & 0xffff));
        a[3] += bf2f((unsigned short)(v[q].y >> 16));
        a[4] += bf2f((unsigned short)(v[q].z & 0xffff));
        a[5] += bf2f((unsigned short)(v[q].z >> 16));
        a[6] += bf2f((unsigned short)(v[q].w & 0xffff));
        a[7] += bf2f((unsigned short)(v[q].w >> 16));
    }
    uint4 o;
    o.x = (unsigned)f2bf(a[0]*0.1f) | ((unsigned)f2bf(a[1]*0.1f) << 16);
    o.y = (unsigned)f2bf(a[2]*0.1f) | ((unsigned)f2bf(a[3]*0.1f) << 16);
    o.z = (unsigned)f2bf(a[4]*0.1f) | ((unsigned)f2bf(a[5]*0.1f) << 16);
    o.w = (unsigned)f2bf(a[6]*0.1f) | ((unsigned)f2bf(a[7]*0.1f) << 16);
    *(uint4*)(dst + node * 256 + d0) = o;
}

// ------- fused: hop-2 gather + BARRIER-FREE-K GEMM + Euler + readout ----------
// R9 exact (best composite 380us): M16 x N256, 512 threads (8 waves),
// grid 512 = 2 blocks/CU = 4 waves/SIMD. B from fragment-major Wt (coalesced,
// no LDS, no K-loop barriers; 2 barriers total). R10/R11: occupancy =
// min(grid, LDS, VGPR) — this config is the local optimum from both sides.
__launch_bounds__(512, 4)
__global__ void gemm_step(unsigned short* hbf,
                          const unsigned short* __restrict__ x1,
                          const int* __restrict__ nbr,
                          const unsigned short* __restrict__ Wt,
                          const float* __restrict__ cb,
                          const float* __restrict__ rw, const float* __restrict__ rb,
                          float* hdo, float* __restrict__ yout, float* yfin) {
    __shared__ __align__(16) short Ah[16 * 264];
    __shared__ __align__(16) short A1[16 * 264];
    __shared__ __align__(16) short X2[16 * 264];
    __shared__ float rwl[768];
    __shared__ float cbl[256];
    __shared__ float yred[8][4][4][3];     // [wave][quad][r][xyz]

    int tid = threadIdx.x;
    int m0 = blockIdx.x * 16;
    for (int idx = tid; idx < 768; idx += 512) rwl[idx] = rw[idx];
    if (tid < 256) cbl[tid] = cb[tid];

    int w = tid >> 6, lane = tid & 63;
    int quad = lane >> 4, l15 = lane & 15;
    int row = tid >> 5, cg = tid & 31;            // stage coords: 16 rows x 32 thr

    // ---- stage A for hop0 (hbf) and hop1 (x1) --------------------------------
    {
        uint4 va = *(const uint4*)(((const unsigned short*)hbf) + (m0 + row) * 256 + cg * 8);
        *(uint4*)((unsigned short*)&Ah[row * 264 + cg * 8]) = va;
        uint4 vb = *(const uint4*)(x1 + (m0 + row) * 256 + cg * 8);
        *(uint4*)((unsigned short*)&A1[row * 264 + cg * 8]) = vb;
    }
    // ---- hop-2 gather: X2[row][:] = bf16(0.1 * sum x1[nbr[row]]) -------------
    {
        const int* nb = nbr + (m0 + row) * KNN;
        int j[KNN];
#pragma unroll
        for (int q = 0; q < KNN; q++) j[q] = nb[q];
        float a[8];
#pragma unroll
        for (int e = 0; e < 8; e++) a[e] = 0.f;
#pragma unroll
        for (int q = 0; q < KNN; q++) {
            uint4 v = *(const uint4*)(x1 + j[q] * 256 + cg * 8);
            a[0] += bf2f((unsigned short)(v.x & 0xffff));
            a[1] += bf2f((unsigned short)(v.x >> 16));
            a[2] += bf2f((unsigned short)(v.y & 0xffff));
            a[3] += bf2f((unsigned short)(v.y >> 16));
            a[4] += bf2f((unsigned short)(v.z & 0xffff));
            a[5] += bf2f((unsigned short)(v.z >> 16));
            a[6] += bf2f((unsigned short)(v.w & 0xffff));
            a[7] += bf2f((unsigned short)(v.w >> 16));
        }
        uint4 o;
        o.x = (unsigned)f2bf(a[0]*0.1f) | ((unsigned)f2bf(a[1]*0.1f) << 16);
        o.y = (unsigned)f2bf(a[2]*0.1f) | ((unsigned)f2bf(a[3]*0.1f) << 16);
        o.z = (unsigned)f2bf(a[4]*0.1f) | ((unsigned)f2bf(a[5]*0.1f) << 16);
        o.w = (unsigned)f2bf(a[6]*0.1f) | ((unsigned)f2bf(a[7]*0.1f) << 16);
        *(uint4*)((unsigned short*)&X2[row * 264 + cg * 8]) = o;
    }
    __syncthreads();      // A buffers ready; K-loop is barrier-free from here

    f4v acc[2];
    acc[0] = (f4v){0.f, 0.f, 0.f, 0.f};
    acc[1] = (f4v){0.f, 0.f, 0.f, 0.f};

#pragma unroll
    for (int kc = 0; kc < 12; kc++) {
        const short* Ab = (kc < 4) ? Ah : (kc < 8) ? A1 : X2;
        int kl = (kc & 3) * 64;
#pragma unroll
        for (int ks = 0; ks < 2; ks++) {
            s8v a = *(const s8v*)(&Ab[l15 * 264 + kl + ks * 32 + quad * 8]);
#pragma unroll
            for (int f = 0; f < 2; f++) {
                // fragment-major B: one coalesced 1KB wave load
                s8v b = *(const s8v*)(Wt + ((kc * 2 + ks) * 16 + (w * 2 + f)) * 512 + lane * 8);
                acc[f] = __builtin_amdgcn_mfma_f32_16x16x32_bf16(a, b, acc[f], 0, 0, 0);
            }
        }
    }

    // ---- epilogue: Euler update + readout partials ---------------------------
    float py[4][3] = {};
#pragma unroll
    for (int f = 0; f < 2; f++) {
        int col = w * 32 + f * 16 + l15;
        float cbv = cbl[col];
        float rw0 = rwl[col * 3], rw1 = rwl[col * 3 + 1], rw2 = rwl[col * 3 + 2];
#pragma unroll
        for (int r = 0; r < 4; r++) {
            int grow = m0 + quad * 4 + r;
            float cval = acc[f][r] + cbv;
            float hn = hdo[grow * 256 + col] + EPSC * tanhf(cval);
            hdo[grow * 256 + col] = hn;
            hbf[grow * 256 + col] = f2bf(hn);
            py[r][0] += hn * rw0; py[r][1] += hn * rw1; py[r][2] += hn * rw2;
        }
    }
    for (int off = 1; off < 16; off <<= 1)
        for (int r = 0; r < 4; r++)
            for (int j = 0; j < 3; j++)
                py[r][j] += __shfl_xor(py[r][j], off, 64);
    if (l15 == 0)
        for (int r = 0; r < 4; r++)
            for (int j = 0; j < 3; j++)
                yred[w][quad][r][j] = py[r][j];
    __syncthreads();
    if (w == 0 && l15 == 0) {
        for (int r = 0; r < 4; r++) {
            int grow = m0 + quad * 4 + r;
            for (int j = 0; j < 3; j++) {
                float yv = rb[j];
                for (int ww = 0; ww < 8; ww++) yv += yred[ww][quad][r][j];
                yout[grow * 3 + j] = yv;
                if (yfin) yfin[grow * 3 + j] = yv;
            }
        }
    }
}

extern "C" void kernel_launch(void* const* d_in, const int* in_sizes, int n_in,
                              void* d_out, int out_size, void* d_ws, size_t ws_size,
                              hipStream_t stream) {
    const float* lm = (const float*)d_in[0];
    const float* ew = (const float*)d_in[1];
    const float* eb = (const float*)d_in[2];
    const float* rw = (const float*)d_in[3];
    const float* rb = (const float*)d_in[4];
    const float* cw = (const float*)d_in[5];
    const float* cb = (const float*)d_in[6];

    float* out = (float*)d_out;
    float* y_out = out;
    float* h_out = out + 24576;
    float* x_out = out + 24576 + 2097152;
    float* lp_out = x_out + 24576;

    char* ws = (char*)d_ws;
    int* nbr = (int*)ws;                       ws += NN * KNN * sizeof(int);
    float4* pos4 = (float4*)ws;                ws += NN * sizeof(float4);
    char* uni = ws;
    unsigned short* hbf = (unsigned short*)uni;
    unsigned short* x1  = hbf + NN * DH;
    unsigned short* Wt  = x1 + NN * DH;

    prep_pos<<<NN / 256, 256, 0, stream>>>(lm, pos4);
    knn_wave<<<NN / QPB, 1024, 0, stream>>>(lm, pos4, nbr);
    prep_wt<<<768, 256, 0, stream>>>(cw, Wt);
    emb_kernel<<<NN, 256, 0, stream>>>(lm, ew, eb, rw, rb, h_out, hbf, x_out);
    for (int t = 0; t < TSTEPS; t++) {
        agg_kernel<<<NN / 8, 256, 0, stream>>>(hbf, x1, nbr);
        gemm_step<<<NN / 16, 512, 0, stream>>>(hbf, x1, nbr, Wt, cb, rw, rb, h_out,
                                               lp_out + t * 24576,
                                               (t == TSTEPS - 1) ? y_out : nullptr);
    }
}